// Round 2
// baseline (1741.835 us; speedup 1.0000x reference)
//
#include <hip/hip_runtime.h>
#include <hip/hip_bf16.h>

// ---------------- problem constants ----------------
#define NPTS 131072          // N = B*NPB
#define CF   128             // channels
#define NH   4               // heads
#define DH   32              // head dim
#define GS   4096            // group size
#define TT   64              // chunk length
#define NGRP 32              // NPTS/GS
#define NCH  64              // GS/TT
#define PER  2738            // mx*my*mz = 37*37*2
#define NBKT 5476            // 2*PER
// window: wx=13, wy=13, wz=32 ; mx=my=37, mz=2

// ---------------- sort kernels ----------------
__global__ void k_zero(int* a, int* b, int* c, int* d) {
    int t = blockIdx.x * 256 + threadIdx.x;
    if (t < 8192) { a[t] = 0; b[t] = 0; c[t] = 0; d[t] = 0; }
}

__global__ void k_keys(const int* __restrict__ coords, int* cntx, int* cnty) {
    int j = blockIdx.x * 256 + threadIdx.x;
    if (j >= NPTS) return;
    int b = coords[4*j], z = coords[4*j+1], y = coords[4*j+2], x = coords[4*j+3];
    int wcx = x / 13, wcy = y / 13, wcz = z / 32;
    int bwx = b * PER + wcx * 74 + wcy * 2 + wcz;   // 74 = my*mz = mx*mz
    int bwy = b * PER + wcy * 74 + wcx * 2 + wcz;
    atomicAdd(&cntx[bwx], 1);
    atomicAdd(&cnty[bwy], 1);
}

__global__ __launch_bounds__(256) void k_scan(const int* __restrict__ cntx, int* offx,
                                              const int* __restrict__ cnty, int* offy) {
    const int* cnt = blockIdx.x ? cnty : cntx;
    int* off = blockIdx.x ? offy : offx;
    __shared__ int part[256];
    int t = threadIdx.x;
    const int CH = (NBKT + 255) / 256;   // 22
    int s = 0;
    for (int i = 0; i < CH; i++) { int idx = t * CH + i; if (idx < NBKT) s += cnt[idx]; }
    part[t] = s;
    __syncthreads();
    for (int d = 1; d < 256; d <<= 1) {
        int v = (t >= d) ? part[t - d] : 0;
        __syncthreads();
        part[t] += v;
        __syncthreads();
    }
    int base = (t == 0) ? 0 : part[t - 1];
    for (int i = 0; i < CH; i++) {
        int idx = t * CH + i;
        if (idx < NBKT) { off[idx] = base; base += cnt[idx]; }
    }
}

__global__ void k_scatter(const int* __restrict__ coords,
                          const int* __restrict__ offx, int* curx, int* bkx,
                          const int* __restrict__ offy, int* cury, int* bky) {
    int j = blockIdx.x * 256 + threadIdx.x;
    if (j >= NPTS) return;
    int b = coords[4*j], z = coords[4*j+1], y = coords[4*j+2], x = coords[4*j+3];
    int wcx = x / 13, wcy = y / 13, wcz = z / 32;
    int cx = x - wcx * 13, cy = y - wcy * 13, cz = z - wcz * 32;
    int bwx = b * PER + wcx * 74 + wcy * 2 + wcz;
    int bwy = b * PER + wcy * 74 + wcx * 2 + wcz;
    int intrax = cx * 416 + cy * 32 + cz;     // cx*(wy*wz)+cy*wz+cz
    int intray = cy * 416 + cx * 32 + cz;     // cy*(wx*wz)+cx*wz+cz
    int px = offx[bwx] + atomicAdd(&curx[bwx], 1);
    bkx[px] = (intrax << 17) | j;
    int py = offy[bwy] + atomicAdd(&cury[bwy], 1);
    bky[py] = (intray << 17) | j;
}

__global__ __launch_bounds__(256) void k_bsort(const int* offx, const int* cntx, const int* bkx, int* ix,
                                               const int* offy, const int* cnty, const int* bky, int* iy) {
    const int* off; const int* cnt; const int* bk; int* oidx;
    if (blockIdx.y == 0) { off = offx; cnt = cntx; bk = bkx; oidx = ix; }
    else                 { off = offy; cnt = cnty; bk = bky; oidx = iy; }
    int b = blockIdx.x;
    int n = cnt[b];
    if (n <= 0) return;
    int base = off[b];
    __shared__ int keys[256];
    int t = threadIdx.x;
    if (t < n) keys[t] = bk[base + t];
    __syncthreads();
    if (t < n) {
        int kv = keys[t];
        int r = 0;
        for (int j = 0; j < n; j++) r += (keys[j] < kv);
        oidx[base + r] = kv & 0x1FFFF;
    }
}

// ---------------- gather ----------------
__global__ __launch_bounds__(256) void k_gather(const float* __restrict__ src,
                                                const int* __restrict__ idx,
                                                float* __restrict__ xs) {
    int tid = blockIdx.x * 256 + threadIdx.x;   // NPTS*32 threads, 4 floats each
    int j = tid >> 5, q = tid & 31;
    if (j >= NPTS) return;
    const float4* s = (const float4*)(src + (size_t)idx[j] * CF);
    ((float4*)(xs + (size_t)j * CF))[q] = s[q];
}

// ---------------- per-chunk KV contribution: A[d][e] = sum_s gamma^(T-1-s) k[s,d] v[s,e] ----------------
__global__ __launch_bounds__(256) void k_chunkkv(const float* __restrict__ xs,
                                                 const float* __restrict__ Wk,
                                                 const float* __restrict__ Wv,
                                                 float* __restrict__ Ab) {
    int gc = blockIdx.x;
    int g = gc >> 6, c = gc & 63;
    __shared__ float X[64][128];
    __shared__ float Kh[64][32];
    __shared__ float Vh[64][32];
    int t = threadIdx.x;
    {
        const float4* xin = (const float4*)(xs + (size_t)(g * GS + c * TT) * CF);
        float4* Xv = (float4*)&X[0][0];
#pragma unroll
        for (int i = 0; i < 8; i++) Xv[t + 256 * i] = xin[t + 256 * i];
    }
    __syncthreads();
    const int cc = t & 31, rg = t >> 5;
    for (int h = 0; h < NH; h++) {
        const float gam = 1.f - exp2f(-5.f - (float)h);
        const float l2g = log2f(gam);
        float ak[8], av[8];
#pragma unroll
        for (int i = 0; i < 8; i++) { ak[i] = 0.f; av[i] = 0.f; }
        const float* wk = Wk + h * 32 + cc;
        const float* wv = Wv + h * 32 + cc;
        for (int k4 = 0; k4 < 32; k4++) {
            float wkv[4], wvv[4];
#pragma unroll
            for (int j = 0; j < 4; j++) { wkv[j] = wk[(k4*4+j)*128]; wvv[j] = wv[(k4*4+j)*128]; }
#pragma unroll
            for (int i = 0; i < 8; i++) {
                float4 xv = *(const float4*)&X[rg*8+i][k4*4];
                ak[i] += xv.x*wkv[0] + xv.y*wkv[1] + xv.z*wkv[2] + xv.w*wkv[3];
                av[i] += xv.x*wvv[0] + xv.y*wvv[1] + xv.z*wvv[2] + xv.w*wvv[3];
            }
        }
#pragma unroll
        for (int i = 0; i < 8; i++) {
            int r = rg * 8 + i;
            Kh[r][cc] = ak[i] * exp2f((float)(63 - r) * l2g);   // kv_d applied
            Vh[r][cc] = av[i];
        }
        __syncthreads();
        float acc[4] = {0.f, 0.f, 0.f, 0.f};
        for (int s = 0; s < 64; s++) {
            float ve = Vh[s][cc];
#pragma unroll
            for (int i = 0; i < 4; i++) acc[i] += Kh[s][rg*4+i] * ve;
        }
        float* aout = Ab + ((size_t)(g * NH + h) * NCH + c) * 1024;
#pragma unroll
        for (int i = 0; i < 4; i++) aout[(rg*4+i)*32 + cc] = acc[i];
        __syncthreads();
    }
}

// ---------------- sequential state scan over chunks (in place: A -> exclusive-prefix S) ----------------
__global__ __launch_bounds__(256) void k_scan_state(float* __restrict__ Ab) {
    int gh = blockIdx.x;           // g*NH + h
    int h = gh & 3;
    float gT = exp2f(64.f * log2f(1.f - exp2f(-5.f - (float)h)));
    float* base = Ab + (size_t)gh * NCH * 1024;
    int t = threadIdx.x;
    float s[4] = {0.f, 0.f, 0.f, 0.f};
    for (int c = 0; c < NCH; c++) {
        float* p = base + c * 1024;
#pragma unroll
        for (int i = 0; i < 4; i++) {
            float a = p[t + i * 256];
            p[t + i * 256] = s[i];
            s[i] = gT * s[i] + a;
        }
    }
}

// ---------------- attention: inner + cross -> Y ----------------
__global__ __launch_bounds__(256) void k_attn(const float* __restrict__ xs,
                                              const float* __restrict__ Wq,
                                              const float* __restrict__ Wk,
                                              const float* __restrict__ Wv,
                                              const float* __restrict__ Sb,
                                              float* __restrict__ Yb) {
    int gc = blockIdx.x;
    int g = gc >> 6, c = gc & 63;
    __shared__ float X[64][128];     // 32KB
    __shared__ float QT[32][64];     // 8KB  (transposed q: QT[d][t])
    __shared__ float B2[2048];       // 8KB  KT[32][64] during attn, then Vh[64][32]
    __shared__ float Att[64][64];    // 16KB
    int t = threadIdx.x;
    {
        const float4* xin = (const float4*)(xs + (size_t)(g * GS + c * TT) * CF);
        float4* Xv = (float4*)&X[0][0];
#pragma unroll
        for (int i = 0; i < 8; i++) Xv[t + 256 * i] = xin[t + 256 * i];
    }
    __syncthreads();
    const int cc = t & 31, rg = t >> 5;
    const size_t tokbase = (size_t)(g * GS + c * TT);
    for (int h = 0; h < NH; h++) {
        const float gam = 1.f - exp2f(-5.f - (float)h);
        const float l2g = log2f(gam);
        // --- Q, K, V gemms: out[r][cc] = sum_k X[r][k] * W[k][h*32+cc] ---
        float aq[8], ak[8], av[8];
#pragma unroll
        for (int i = 0; i < 8; i++) { aq[i] = 0.f; ak[i] = 0.f; av[i] = 0.f; }
        const float* wq = Wq + h * 32 + cc;
        const float* wk = Wk + h * 32 + cc;
        const float* wv = Wv + h * 32 + cc;
        for (int k4 = 0; k4 < 32; k4++) {
            float wqv[4], wkv[4], wvv[4];
#pragma unroll
            for (int j = 0; j < 4; j++) {
                wqv[j] = wq[(k4*4+j)*128];
                wkv[j] = wk[(k4*4+j)*128];
                wvv[j] = wv[(k4*4+j)*128];
            }
#pragma unroll
            for (int i = 0; i < 8; i++) {
                float4 xv = *(const float4*)&X[rg*8+i][k4*4];
                aq[i] += xv.x*wqv[0] + xv.y*wqv[1] + xv.z*wqv[2] + xv.w*wqv[3];
                ak[i] += xv.x*wkv[0] + xv.y*wkv[1] + xv.z*wkv[2] + xv.w*wkv[3];
                av[i] += xv.x*wvv[0] + xv.y*wvv[1] + xv.z*wvv[2] + xv.w*wvv[3];
            }
        }
#pragma unroll
        for (int i = 0; i < 8; i++) {
            int r = rg * 8 + i;
            QT[cc][r] = aq[i] * 0.17677669529663687f;   // * DH^-0.5
            B2[cc * 64 + r] = ak[i];                    // KT[d=cc][s=r]
        }
        __syncthreads();
        // --- Att[r][s] = D(r,s) * sum_k q[r,k] k[s,k] ---
        {
            int r2 = t >> 2, sq = t & 3;
            float qreg[32];
#pragma unroll
            for (int k = 0; k < 32; k++) qreg[k] = QT[k][r2];
            for (int i = 0; i < 16; i++) {
                int s = i * 4 + sq;
                float acc = 0.f;
#pragma unroll
                for (int k = 0; k < 32; k++) acc += qreg[k] * B2[k * 64 + s];
                float dd = (r2 >= s) ? exp2f((float)(r2 - s) * l2g) : 0.f;
                Att[r2][s] = acc * dd;
            }
        }
        __syncthreads();   // Att complete; K reads complete
        // --- cross: out[r][cc] = gamma^(r+1) * sum_d q[r,d] S[d,cc] ---
        float outr[8];
        {
            const float* S = Sb + ((size_t)(g * NH + h) * NCH + c) * 1024;
            float cr[8];
#pragma unroll
            for (int i = 0; i < 8; i++) cr[i] = 0.f;
            for (int d = 0; d < 32; d++) {
                float sv = S[d * 32 + cc];
#pragma unroll
                for (int i = 0; i < 8; i++) cr[i] += QT[d][rg*8+i] * sv;
            }
#pragma unroll
            for (int i = 0; i < 8; i++) outr[i] = cr[i] * exp2f((float)(rg*8+i+1) * l2g);
        }
        // --- V into B2 row-major ---
#pragma unroll
        for (int i = 0; i < 8; i++) B2[(rg*8+i)*32 + cc] = av[i];
        __syncthreads();
        // --- inner: out[r][cc] += sum_s Att[r][s] V[s][cc] ---
        for (int s = 0; s < 64; s++) {
            float vv = B2[s * 32 + cc];
#pragma unroll
            for (int i = 0; i < 8; i++) outr[i] += Att[rg*8+i][s] * vv;
        }
        float* yo = Yb + tokbase * CF + h * 32 + cc;
#pragma unroll
        for (int i = 0; i < 8; i++) yo[(size_t)(rg*8+i) * CF] = outr[i];
        __syncthreads();
    }
}

// ---------------- final: out[idx[r]] = x + (Y * silu(x@Wg)) @ Wo ----------------
__global__ __launch_bounds__(256) void k_final(const float* __restrict__ xs,
                                               const float* __restrict__ Yb,
                                               const float* __restrict__ Wg,
                                               const float* __restrict__ Wo,
                                               const int* __restrict__ idx,
                                               float* __restrict__ outp) {
    size_t tb = (size_t)blockIdx.x * 64;
    __shared__ float Xl[64][128];
    __shared__ float Zl[64][128];
    int t = threadIdx.x;
    {
        const float4* xin = (const float4*)(xs + tb * CF);
        float4* Xv = (float4*)&Xl[0][0];
#pragma unroll
        for (int i = 0; i < 8; i++) Xv[t + 256 * i] = xin[t + 256 * i];
    }
    __syncthreads();
    const int c4 = (t & 31) * 4, rg = t >> 5;
    {
        float acc[8][4];
#pragma unroll
        for (int i = 0; i < 8; i++) { acc[i][0]=0.f; acc[i][1]=0.f; acc[i][2]=0.f; acc[i][3]=0.f; }
        for (int k4 = 0; k4 < 32; k4++) {
            float4 w0 = *(const float4*)&Wg[(k4*4+0)*128 + c4];
            float4 w1 = *(const float4*)&Wg[(k4*4+1)*128 + c4];
            float4 w2 = *(const float4*)&Wg[(k4*4+2)*128 + c4];
            float4 w3 = *(const float4*)&Wg[(k4*4+3)*128 + c4];
#pragma unroll
            for (int i = 0; i < 8; i++) {
                float4 xv = *(const float4*)&Xl[rg*8+i][k4*4];
                acc[i][0] += xv.x*w0.x + xv.y*w1.x + xv.z*w2.x + xv.w*w3.x;
                acc[i][1] += xv.x*w0.y + xv.y*w1.y + xv.z*w2.y + xv.w*w3.y;
                acc[i][2] += xv.x*w0.z + xv.y*w1.z + xv.z*w2.z + xv.w*w3.z;
                acc[i][3] += xv.x*w0.w + xv.y*w1.w + xv.z*w2.w + xv.w*w3.w;
            }
        }
#pragma unroll
        for (int i = 0; i < 8; i++) {
            int r = rg * 8 + i;
            float4 yv = *(const float4*)&Yb[(tb + r) * CF + c4];
            float4 z;
            z.x = yv.x * (acc[i][0] / (1.f + __expf(-acc[i][0])));
            z.y = yv.y * (acc[i][1] / (1.f + __expf(-acc[i][1])));
            z.z = yv.z * (acc[i][2] / (1.f + __expf(-acc[i][2])));
            z.w = yv.w * (acc[i][3] / (1.f + __expf(-acc[i][3])));
            *(float4*)&Zl[r][c4] = z;
        }
    }
    __syncthreads();
    {
        float acc[8][4];
#pragma unroll
        for (int i = 0; i < 8; i++) { acc[i][0]=0.f; acc[i][1]=0.f; acc[i][2]=0.f; acc[i][3]=0.f; }
        for (int k4 = 0; k4 < 32; k4++) {
            float4 w0 = *(const float4*)&Wo[(k4*4+0)*128 + c4];
            float4 w1 = *(const float4*)&Wo[(k4*4+1)*128 + c4];
            float4 w2 = *(const float4*)&Wo[(k4*4+2)*128 + c4];
            float4 w3 = *(const float4*)&Wo[(k4*4+3)*128 + c4];
#pragma unroll
            for (int i = 0; i < 8; i++) {
                float4 zv = *(const float4*)&Zl[rg*8+i][k4*4];
                acc[i][0] += zv.x*w0.x + zv.y*w1.x + zv.z*w2.x + zv.w*w3.x;
                acc[i][1] += zv.x*w0.y + zv.y*w1.y + zv.z*w2.y + zv.w*w3.y;
                acc[i][2] += zv.x*w0.z + zv.y*w1.z + zv.z*w2.z + zv.w*w3.z;
                acc[i][3] += zv.x*w0.w + zv.y*w1.w + zv.z*w2.w + zv.w*w3.w;
            }
        }
#pragma unroll
        for (int i = 0; i < 8; i++) {
            int r = rg * 8 + i;
            float4 xv = *(const float4*)&Xl[r][c4];
            float4 o;
            o.x = xv.x + acc[i][0];
            o.y = xv.y + acc[i][1];
            o.z = xv.z + acc[i][2];
            o.w = xv.w + acc[i][3];
            *(float4*)&outp[(size_t)idx[tb + r] * CF + c4] = o;
        }
    }
}

// ---------------- host side ----------------
static void run_pass(const float* src, const int* idx,
                     const float* Wq, const float* Wk, const float* Wv,
                     const float* Wg, const float* Wo,
                     float* xs, float* Yb, float* Ab, float* out, hipStream_t stream) {
    k_gather<<<16384, 256, 0, stream>>>(src, idx, xs);
    k_chunkkv<<<NGRP * NCH, 256, 0, stream>>>(xs, Wk, Wv, Ab);
    k_scan_state<<<NGRP * NH, 256, 0, stream>>>(Ab);
    k_attn<<<NGRP * NCH, 256, 0, stream>>>(xs, Wq, Wk, Wv, Ab, Yb);
    k_final<<<NPTS / 64, 256, 0, stream>>>(xs, Yb, Wg, Wo, idx, out);
}

extern "C" void kernel_launch(void* const* d_in, const int* in_sizes, int n_in,
                              void* d_out, int out_size, void* d_ws, size_t ws_size,
                              hipStream_t stream) {
    const float* feats  = (const float*)d_in[0];
    const int*   coords = (const int*)d_in[1];
    const float* W[10];
    for (int i = 0; i < 10; i++) W[i] = (const float*)d_in[2 + i];
    float* out = (float*)d_out;

    char* w = (char*)d_ws;
    float* xs  = (float*)w; w += (size_t)NPTS * CF * 4;                  // 64 MB
    float* Yb  = (float*)w; w += (size_t)NPTS * CF * 4;                  // 64 MB
    float* Ab  = (float*)w; w += (size_t)NGRP * NH * NCH * 1024 * 4;     // 32 MB
    int* ix   = (int*)w; w += (size_t)NPTS * 4;
    int* iy   = (int*)w; w += (size_t)NPTS * 4;
    int* bkx  = (int*)w; w += (size_t)NPTS * 4;
    int* bky  = (int*)w; w += (size_t)NPTS * 4;
    int* cntx = (int*)w; w += 8192 * 4;
    int* cnty = (int*)w; w += 8192 * 4;
    int* offx = (int*)w; w += 8192 * 4;
    int* offy = (int*)w; w += 8192 * 4;
    int* curx = (int*)w; w += 8192 * 4;
    int* cury = (int*)w; w += 8192 * 4;

    // ---- stable argsort of both space-filling keys ----
    k_zero<<<32, 256, 0, stream>>>(cntx, cnty, curx, cury);
    k_keys<<<(NPTS + 255) / 256, 256, 0, stream>>>(coords, cntx, cnty);
    k_scan<<<2, 256, 0, stream>>>(cntx, offx, cnty, offy);
    k_scatter<<<(NPTS + 255) / 256, 256, 0, stream>>>(coords, offx, curx, bkx, offy, cury, bky);
    k_bsort<<<dim3(NBKT, 2), 256, 0, stream>>>(offx, cntx, bkx, ix, offy, cnty, bky, iy);

    // ---- pass 0 (x-order): feats -> out ----
    run_pass(feats, ix, W[0], W[1], W[2], W[3], W[4], xs, Yb, Ab, out, stream);
    // ---- pass 1 (y-order): out -> out ----
    run_pass(out,   iy, W[5], W[6], W[7], W[8], W[9], xs, Yb, Ab, out, stream);
}

// Round 4
// 648.318 us; speedup vs baseline: 2.6867x; 2.6867x over previous
//
#include <hip/hip_runtime.h>
#include <hip/hip_bf16.h>

// ---------------- problem constants ----------------
#define NPTS 131072
#define CF   128
#define GS   4096
#define PER  2738            // 37*37*2
#define NBKT 5476
#define NCHUNK 2048          // NPTS/64

typedef short v8s __attribute__((ext_vector_type(8)));
typedef float v4f __attribute__((ext_vector_type(4)));
#define MFMA16(a,b,c) __builtin_amdgcn_mfma_f32_16x16x32_bf16(a,b,c,0,0,0)

__device__ __forceinline__ unsigned short f2b(float x) {
    unsigned u = __float_as_uint(x);
    unsigned r = (u + 0x7FFFu + ((u >> 16) & 1u)) >> 16;
    return (unsigned short)r;
}
__device__ __forceinline__ unsigned pack2(float a, float b) {
    return (unsigned)f2b(a) | ((unsigned)f2b(b) << 16);
}
__device__ __forceinline__ float b2f(unsigned short s) {
    return __uint_as_float((unsigned)s << 16);
}

// ---------------- sort kernels (unchanged, verified) ----------------
__global__ void k_zero(int* a, int* b, int* c, int* d) {
    int t = blockIdx.x * 256 + threadIdx.x;
    if (t < 8192) { a[t] = 0; b[t] = 0; c[t] = 0; d[t] = 0; }
}

__global__ void k_keys(const int* __restrict__ coords, int* cntx, int* cnty) {
    int j = blockIdx.x * 256 + threadIdx.x;
    if (j >= NPTS) return;
    int b = coords[4*j], z = coords[4*j+1], y = coords[4*j+2], x = coords[4*j+3];
    int wcx = x / 13, wcy = y / 13, wcz = z / 32;
    atomicAdd(&cntx[b * PER + wcx * 74 + wcy * 2 + wcz], 1);
    atomicAdd(&cnty[b * PER + wcy * 74 + wcx * 2 + wcz], 1);
}

__global__ __launch_bounds__(256) void k_bscan(const int* __restrict__ cntx, int* offx,
                                               const int* __restrict__ cnty, int* offy) {
    const int* cnt = blockIdx.x ? cnty : cntx;
    int* off = blockIdx.x ? offy : offx;
    __shared__ int part[256];
    int t = threadIdx.x;
    const int CH = (NBKT + 255) / 256;
    int s = 0;
    for (int i = 0; i < CH; i++) { int idx = t * CH + i; if (idx < NBKT) s += cnt[idx]; }
    part[t] = s;
    __syncthreads();
    for (int d = 1; d < 256; d <<= 1) {
        int v = (t >= d) ? part[t - d] : 0;
        __syncthreads();
        part[t] += v;
        __syncthreads();
    }
    int base = (t == 0) ? 0 : part[t - 1];
    for (int i = 0; i < CH; i++) {
        int idx = t * CH + i;
        if (idx < NBKT) { off[idx] = base; base += cnt[idx]; }
    }
}

__global__ void k_scatter(const int* __restrict__ coords,
                          const int* __restrict__ offx, int* curx, int* bkx,
                          const int* __restrict__ offy, int* cury, int* bky) {
    int j = blockIdx.x * 256 + threadIdx.x;
    if (j >= NPTS) return;
    int b = coords[4*j], z = coords[4*j+1], y = coords[4*j+2], x = coords[4*j+3];
    int wcx = x / 13, wcy = y / 13, wcz = z / 32;
    int cx = x - wcx * 13, cy = y - wcy * 13, cz = z - wcz * 32;
    int px = offx[b*PER + wcx*74 + wcy*2 + wcz] + atomicAdd(&curx[b*PER + wcx*74 + wcy*2 + wcz], 1);
    bkx[px] = ((cx * 416 + cy * 32 + cz) << 17) | j;
    int py = offy[b*PER + wcy*74 + wcx*2 + wcz] + atomicAdd(&cury[b*PER + wcy*74 + wcx*2 + wcz], 1);
    bky[py] = ((cy * 416 + cx * 32 + cz) << 17) | j;
}

__global__ __launch_bounds__(256) void k_bsort(const int* offx, const int* cntx, const int* bkx, int* ix,
                                               const int* offy, const int* cnty, const int* bky, int* iy) {
    const int* off; const int* cnt; const int* bk; int* oidx;
    if (blockIdx.y == 0) { off = offx; cnt = cntx; bk = bkx; oidx = ix; }
    else                 { off = offy; cnt = cnty; bk = bky; oidx = iy; }
    int b = blockIdx.x;
    int n = cnt[b];
    if (n <= 0) return;
    int base = off[b];
    __shared__ int keys[256];
    int t = threadIdx.x;
    if (t < n) keys[t] = bk[base + t];
    __syncthreads();
    if (t < n) {
        int kv = keys[t];
        int r = 0;
        for (int j = 0; j < n; j++) r += (keys[j] < kv);
        oidx[base + r] = kv & 0x1FFFF;
    }
}

// ---------------- weight convert+transpose: WT[w][d][c] = W[w][c][d] (bf16) ----------------
struct WP { const float* p[10]; };
__global__ void k_cvtw(WP wp, unsigned short* __restrict__ WT) {
    int i = blockIdx.x * 256 + threadIdx.x;   // 10*16384
    int w = i >> 14, r = i & 16383, c = r >> 7, d = r & 127;
    float v = wp.p[w][c * 128 + d];
    if (w == 0 || w == 5) v *= 0.17677669529663687f;   // fold DH^-0.5 into Wq
    WT[(size_t)w * 16384 + d * 128 + c] = f2b(v);
}

// ---------------- qkvA: Q,K,V projections (MFMA) + decayed chunk K^T V ----------------
// Q,K swapped-form -> row-major qb/kb [tok][128]; V normal-form -> vtb [chunk][h][e][s].
// A_mat[d][e] = sum_s gamma^(63-s) K[s,d] V[s,e]  stored transposed: At[..][e*32+d].
__global__ __launch_bounds__(256) void k_qkvA(const float* __restrict__ src,
        const int* __restrict__ idx,
        const unsigned short* __restrict__ WTq, const unsigned short* __restrict__ WTk,
        const unsigned short* __restrict__ WTv,
        unsigned short* __restrict__ qb, unsigned short* __restrict__ kb,
        unsigned short* __restrict__ vtb, float* __restrict__ At) {
    __shared__ unsigned short kt[128 * 72];   // decayed K^T [d][s], pad 72
    __shared__ unsigned short vt[128 * 72];   // V^T [e][s]
    const int chunk = blockIdx.x;
    const int t = threadIdx.x, w = t >> 6, lane = t & 63, l15 = lane & 15, kg = lane >> 4;
    const int rtok = chunk * 64 + w * 16 + l15;
    const int srow = idx[rtok];
    const int sloc = w * 16 + l15;            // token pos within chunk
    // decay gamma_h^(63-sloc) per head
    float w63[4];
#pragma unroll
    for (int h = 0; h < 4; h++) {
        float l2g = log2f(1.f - exp2f(-5.f - (float)h));
        w63[h] = exp2f((float)(63 - sloc) * l2g);
    }
    // X fragments (dual A/B role)
    v8s xf[4];
    const float* xr = src + (size_t)srow * 128;
#pragma unroll
    for (int ks = 0; ks < 4; ks++) {
        int c0 = ks * 32 + kg * 8;
        float4 a = *(const float4*)(xr + c0);
        float4 b = *(const float4*)(xr + c0 + 4);
        v8s v;
        v[0]=(short)f2b(a.x); v[1]=(short)f2b(a.y); v[2]=(short)f2b(a.z); v[3]=(short)f2b(a.w);
        v[4]=(short)f2b(b.x); v[5]=(short)f2b(b.y); v[6]=(short)f2b(b.z); v[7]=(short)f2b(b.w);
        xf[ks] = v;
    }
    // ---- Q (swapped: qT[d][r], D col = token) ----
#pragma unroll
    for (int dt = 0; dt < 8; dt++) {
        v4f acc = {0.f, 0.f, 0.f, 0.f};
#pragma unroll
        for (int ks = 0; ks < 4; ks++) {
            v8s wf = *(const v8s*)(WTq + (size_t)(dt * 16 + l15) * 128 + ks * 32 + kg * 8);
            acc = MFMA16(wf, xf[ks], acc);
        }
        int2 p; p.x = pack2(acc[0], acc[1]); p.y = pack2(acc[2], acc[3]);
        *(int2*)(qb + (size_t)rtok * 128 + dt * 16 + kg * 4) = p;
    }
    // ---- K (swapped) -> kb rows + decayed kt LDS ----
#pragma unroll
    for (int dt = 0; dt < 8; dt++) {
        v4f acc = {0.f, 0.f, 0.f, 0.f};
#pragma unroll
        for (int ks = 0; ks < 4; ks++) {
            v8s wf = *(const v8s*)(WTk + (size_t)(dt * 16 + l15) * 128 + ks * 32 + kg * 8);
            acc = MFMA16(wf, xf[ks], acc);
        }
        int2 p; p.x = pack2(acc[0], acc[1]); p.y = pack2(acc[2], acc[3]);
        *(int2*)(kb + (size_t)rtok * 128 + dt * 16 + kg * 4) = p;
        float dec = w63[dt >> 1];
        int d0 = dt * 16 + kg * 4;
#pragma unroll
        for (int j = 0; j < 4; j++) kt[(d0 + j) * 72 + sloc] = f2b(acc[j] * dec);
    }
    // ---- V (normal: v[s][e], D row = token) -> vtb + vt LDS ----
#pragma unroll
    for (int et = 0; et < 8; et++) {
        v4f acc = {0.f, 0.f, 0.f, 0.f};
#pragma unroll
        for (int ks = 0; ks < 4; ks++) {
            v8s wf = *(const v8s*)(WTv + (size_t)(et * 16 + l15) * 128 + ks * 32 + kg * 8);
            acc = MFMA16(xf[ks], wf, acc);
        }
        int e_glob = et * 16 + l15, h = e_glob >> 5, e = e_glob & 31, s0 = w * 16 + kg * 4;
        int2 p; p.x = pack2(acc[0], acc[1]); p.y = pack2(acc[2], acc[3]);
        *(int2*)(vtb + ((size_t)(chunk * 4 + h) * 2048) + e * 64 + s0) = p;
        *(int2*)(vt + e_glob * 72 + s0) = p;
    }
    __syncthreads();
    // ---- chunk A via MFMA: wave w = head w ----
    {
        int h = w, g = chunk >> 6, c = chunk & 63;
        size_t base = ((size_t)(g * 4 + h) * 64 + c) * 1024;
#pragma unroll
        for (int dt2 = 0; dt2 < 2; dt2++)
#pragma unroll
        for (int et2 = 0; et2 < 2; et2++) {
            v4f acc = {0.f, 0.f, 0.f, 0.f};
#pragma unroll
            for (int ks2 = 0; ks2 < 2; ks2++) {
                v8s af = *(const v8s*)(kt + (h * 32 + dt2 * 16 + l15) * 72 + ks2 * 32 + kg * 8);
                v8s bf = *(const v8s*)(vt + (h * 32 + et2 * 16 + l15) * 72 + ks2 * 32 + kg * 8);
                acc = MFMA16(af, bf, acc);
            }
            *(v4f*)(At + base + (et2 * 16 + l15) * 32 + dt2 * 16 + kg * 4) = acc;
        }
    }
}

// ---------------- serial state scan (exclusive prefix with gamma^64 decay) ----------------
__global__ __launch_bounds__(256) void k_sscan(const float* __restrict__ At,
                                               unsigned short* __restrict__ Sbt) {
    int b = blockIdx.x, gh = b >> 2, q = b & 3, h = gh & 3;
    int p = q * 256 + threadIdx.x;
    float gT = exp2f(64.f * log2f(1.f - exp2f(-5.f - (float)h)));
    size_t base = (size_t)gh * 64 * 1024 + p;
    float s = 0.f;
#pragma unroll 4
    for (int c = 0; c < 64; c++) {
        float a = At[base + (size_t)c * 1024];
        Sbt[base + (size_t)c * 1024] = f2b(s);
        s = gT * s + a;
    }
}

// ---------------- fused attention + gate + output + residual + scatter ----------------
__global__ __launch_bounds__(256) void k_attnf(const float* __restrict__ src,
        const int* __restrict__ idx,
        const unsigned short* __restrict__ qb, const unsigned short* __restrict__ kb,
        const unsigned short* __restrict__ vtb, const unsigned short* __restrict__ Sbt,
        const unsigned short* __restrict__ WTg, const unsigned short* __restrict__ WTo,
        float* __restrict__ outp) {
    __shared__ float gp[4][144];               // gamma_h^(m-64)
    __shared__ unsigned short Pl[64 * 104];    // P-ext row-major [r][96], pad 104
    __shared__ unsigned short VTl[32 * 104];   // Vext^T [e][96], pad 104
    __shared__ unsigned short Zl[64 * 136];    // z row-major [r][128], pad 136
    const int chunk = blockIdx.x;
    const int t = threadIdx.x, w = t >> 6, lane = t & 63, l15 = lane & 15, kg = lane >> 4;
    const int rl = w * 16 + l15;               // local token (row) this lane owns
    const int rtok = chunk * 64 + rl;
    const int srow = idx[rtok];
    {
        float l2gv[4];
#pragma unroll
        for (int h = 0; h < 4; h++) l2gv[h] = log2f(1.f - exp2f(-5.f - (float)h));
        for (int i = t; i < 576; i += 256) {
            int h = i / 144, m = i - h * 144;
            gp[h][m] = exp2f((float)(m - 64) * l2gv[h]);
        }
    }
    v4f yacc[8];
#pragma unroll
    for (int i = 0; i < 8; i++) yacc[i] = (v4f){0.f, 0.f, 0.f, 0.f};

    const size_t sb_base = ((size_t)((chunk >> 6) * 4) * 64 + (chunk & 63)) * 1024;
#pragma unroll
    for (int h = 0; h < 4; h++) {
        __syncthreads();   // gp ready (h=0) / prev-head PV done before VTl restage
        {   // stage V^T rows (this head) and S^T
            int e = t >> 3, s0 = (t & 7) * 8;
            v8s vv = *(const v8s*)(vtb + (size_t)(chunk * 4 + h) * 2048 + e * 64 + s0);
            *(v8s*)(VTl + e * 104 + s0) = vv;
            if (t < 128) {
                int e2 = t >> 2, d0 = (t & 3) * 8;
                v8s sv = *(const v8s*)(Sbt + sb_base + (size_t)h * 64 * 1024 + e2 * 32 + d0);
                *(v8s*)(VTl + e2 * 104 + 64 + d0) = sv;
            }
        }
        __syncthreads();
        // q fragment (B-operand; also the Pc source)
        v8s qf = *(const v8s*)(qb + (size_t)rtok * 128 + h * 32 + kg * 8);
        // QK^T swapped: T[s][r], wave owns col-strip r
        v4f Tf[4];
#pragma unroll
        for (int st = 0; st < 4; st++) {
            v8s kf = *(const v8s*)(kb + (size_t)(chunk * 64 + st * 16 + l15) * 128 + h * 32 + kg * 8);
            Tf[st] = MFMA16(kf, qf, ((v4f){0.f, 0.f, 0.f, 0.f}));
        }
        // decay + P write (packed, wave-exclusive rows)
        float gi1 = gp[h][63], gi2 = gp[h][62], gi3 = gp[h][61];   // gamma^-1,-2,-3
#pragma unroll
        for (int st = 0; st < 4; st++) {
            int s0 = st * 16 + kg * 4;
            float g0 = gp[h][64 + rl - s0];
            float v0 = (rl >= s0    ) ? Tf[st][0] * g0       : 0.f;
            float v1 = (rl >= s0 + 1) ? Tf[st][1] * g0 * gi1 : 0.f;
            float v2 = (rl >= s0 + 2) ? Tf[st][2] * g0 * gi2 : 0.f;
            float v3 = (rl >= s0 + 3) ? Tf[st][3] * g0 * gi3 : 0.f;
            int2 p; p.x = pack2(v0, v1); p.y = pack2(v2, v3);
            *(int2*)(Pl + rl * 104 + s0) = p;
        }
        {   // P-ext: gamma^(r+1) * q_hat
            float gc = gp[h][65 + rl];
            float q0 = b2f((unsigned short)qf[0]) * gc, q1 = b2f((unsigned short)qf[1]) * gc;
            float q2 = b2f((unsigned short)qf[2]) * gc, q3 = b2f((unsigned short)qf[3]) * gc;
            float q4 = b2f((unsigned short)qf[4]) * gc, q5 = b2f((unsigned short)qf[5]) * gc;
            float q6 = b2f((unsigned short)qf[6]) * gc, q7 = b2f((unsigned short)qf[7]) * gc;
            int2 pa; pa.x = pack2(q0, q1); pa.y = pack2(q2, q3);
            *(int2*)(Pl + rl * 104 + 64 + kg * 8) = pa;
            int2 pb; pb.x = pack2(q4, q5); pb.y = pack2(q6, q7);
            *(int2*)(Pl + rl * 104 + 64 + kg * 8 + 4) = pb;
        }
        // PV (+cross): yT[e][r] over k=96
#pragma unroll
        for (int et = 0; et < 2; et++) {
            v4f acc = yacc[h * 2 + et];
#pragma unroll
            for (int ks = 0; ks < 3; ks++) {
                v8s vf = *(const v8s*)(VTl + (et * 16 + l15) * 104 + ks * 32 + kg * 8);
                v8s pf = *(const v8s*)(Pl + rl * 104 + ks * 32 + kg * 8);
                acc = MFMA16(vf, pf, acc);
            }
            yacc[h * 2 + et] = acc;
        }
    }
    // ---- gate: gT[c][r] = (X@Wg)[r][c]; z = y * silu(g) -> Zl (wave-exclusive rows) ----
    v8s xg[4];
    {
        const float* xr = src + (size_t)srow * 128;
#pragma unroll
        for (int ks = 0; ks < 4; ks++) {
            int c0 = ks * 32 + kg * 8;
            float4 a = *(const float4*)(xr + c0);
            float4 b = *(const float4*)(xr + c0 + 4);
            v8s v;
            v[0]=(short)f2b(a.x); v[1]=(short)f2b(a.y); v[2]=(short)f2b(a.z); v[3]=(short)f2b(a.w);
            v[4]=(short)f2b(b.x); v[5]=(short)f2b(b.y); v[6]=(short)f2b(b.z); v[7]=(short)f2b(b.w);
            xg[ks] = v;
        }
    }
#pragma unroll
    for (int ct = 0; ct < 8; ct++) {
        v4f g = {0.f, 0.f, 0.f, 0.f};
#pragma unroll
        for (int ks = 0; ks < 4; ks++) {
            v8s wf = *(const v8s*)(WTg + (size_t)(ct * 16 + l15) * 128 + ks * 32 + kg * 8);
            g = MFMA16(wf, xg[ks], g);
        }
        v4f yv = yacc[ct];
        float z0 = yv[0] * (g[0] / (1.f + __expf(-g[0])));
        float z1 = yv[1] * (g[1] / (1.f + __expf(-g[1])));
        float z2 = yv[2] * (g[2] / (1.f + __expf(-g[2])));
        float z3 = yv[3] * (g[3] / (1.f + __expf(-g[3])));
        int2 p; p.x = pack2(z0, z1); p.y = pack2(z2, z3);
        *(int2*)(Zl + rl * 136 + ct * 16 + kg * 4) = p;
    }
    // ---- out: outT[co][r] = (z@Wo)[r][co]; + residual; scatter ----
    v8s zf[4];
#pragma unroll
    for (int ks = 0; ks < 4; ks++)
        zf[ks] = *(const v8s*)(Zl + rl * 136 + ks * 32 + kg * 8);
    const float* xr = src + (size_t)srow * 128;
#pragma unroll
    for (int cot = 0; cot < 8; cot++) {
        v4f acc = {0.f, 0.f, 0.f, 0.f};
#pragma unroll
        for (int ks = 0; ks < 4; ks++) {
            v8s wf = *(const v8s*)(WTo + (size_t)(cot * 16 + l15) * 128 + ks * 32 + kg * 8);
            acc = MFMA16(wf, zf[ks], acc);
        }
        int c0 = cot * 16 + kg * 4;
        float4 xres = *(const float4*)(xr + c0);
        float4 o;
        o.x = xres.x + acc[0]; o.y = xres.y + acc[1];
        o.z = xres.z + acc[2]; o.w = xres.w + acc[3];
        *(float4*)(outp + (size_t)srow * 128 + c0) = o;
    }
}

// ---------------- host side ----------------
static void run_pass(const float* src, const int* idx, const unsigned short* WT, int wbase,
                     unsigned short* qb, unsigned short* kb, unsigned short* vtb,
                     float* At, unsigned short* Sbt, float* out, hipStream_t stream) {
    k_qkvA<<<NCHUNK, 256, 0, stream>>>(src, idx, WT + (size_t)(wbase+0)*16384,
                                       WT + (size_t)(wbase+1)*16384, WT + (size_t)(wbase+2)*16384,
                                       qb, kb, vtb, At);
    k_sscan<<<512, 256, 0, stream>>>(At, Sbt);
    k_attnf<<<NCHUNK, 256, 0, stream>>>(src, idx, qb, kb, vtb, Sbt,
                                        WT + (size_t)(wbase+3)*16384, WT + (size_t)(wbase+4)*16384, out);
}

extern "C" void kernel_launch(void* const* d_in, const int* in_sizes, int n_in,
                              void* d_out, int out_size, void* d_ws, size_t ws_size,
                              hipStream_t stream) {
    const float* feats  = (const float*)d_in[0];
    const int*   coords = (const int*)d_in[1];
    float* out = (float*)d_out;

    char* wptr = (char*)d_ws;
    unsigned short* qb  = (unsigned short*)wptr; wptr += (size_t)NPTS * 128 * 2;   // 32MB
    unsigned short* kb  = (unsigned short*)wptr; wptr += (size_t)NPTS * 128 * 2;   // 32MB
    unsigned short* vtb = (unsigned short*)wptr; wptr += (size_t)NPTS * 128 * 2;   // 32MB
    float* At           = (float*)wptr;          wptr += (size_t)NCHUNK * 4096 * 4; // 32MB
    unsigned short* Sbt = (unsigned short*)wptr; wptr += (size_t)NCHUNK * 4096 * 2; // 16MB
    unsigned short* WT  = (unsigned short*)wptr; wptr += (size_t)10 * 16384 * 2;    // 320KB
    int* ix   = (int*)wptr; wptr += (size_t)NPTS * 4;
    int* iy   = (int*)wptr; wptr += (size_t)NPTS * 4;
    int* bkx  = (int*)wptr; wptr += (size_t)NPTS * 4;
    int* bky  = (int*)wptr; wptr += (size_t)NPTS * 4;
    int* cntx = (int*)wptr; wptr += 8192 * 4;
    int* cnty = (int*)wptr; wptr += 8192 * 4;
    int* offx = (int*)wptr; wptr += 8192 * 4;
    int* offy = (int*)wptr; wptr += 8192 * 4;
    int* curx = (int*)wptr; wptr += 8192 * 4;
    int* cury = (int*)wptr; wptr += 8192 * 4;

    // weights -> transposed bf16
    WP wp;
    for (int i = 0; i < 10; i++) wp.p[i] = (const float*)d_in[2 + i];
    k_cvtw<<<640, 256, 0, stream>>>(wp, WT);

    // stable argsort of both keys
    k_zero<<<32, 256, 0, stream>>>(cntx, cnty, curx, cury);
    k_keys<<<(NPTS + 255) / 256, 256, 0, stream>>>(coords, cntx, cnty);
    k_bscan<<<2, 256, 0, stream>>>(cntx, offx, cnty, offy);
    k_scatter<<<(NPTS + 255) / 256, 256, 0, stream>>>(coords, offx, curx, bkx, offy, cury, bky);
    k_bsort<<<dim3(NBKT, 2), 256, 0, stream>>>(offx, cntx, bkx, ix, offy, cnty, bky, iy);

    // pass 0 (x-order): feats -> out ; pass 1 (y-order): out -> out
    run_pass(feats, ix, WT, 0, qb, kb, vtb, At, Sbt, out, stream);
    run_pass(out,   iy, WT, 5, qb, kb, vtb, At, Sbt, out, stream);
}